// Round 4
// baseline (2538.265 us; speedup 1.0000x reference)
//
#include <hip/hip_runtime.h>
#include <hip/hip_bf16.h>
#include <stdint.h>

typedef __attribute__((ext_vector_type(8))) __bf16 bf16x8;
typedef __attribute__((ext_vector_type(4))) float  floatx4;

#define T_STEPS 256
#define BATCH   128
#define HID     512

__device__ __forceinline__ float sigmoidf_(float x) { return 1.f / (1.f + __expf(-x)); }
__device__ __forceinline__ float tanhf_(float y) {
  float e = __expf(-2.f * fabsf(y));
  return copysignf((1.f - e) / (1.f + e), y);
}

// Own-ring poll: lane l watches line (l&31) of a 32-line ring.
// FAST: sc0 loads (bypass L1, hit the XCD-shared L2 where ring peers' plain
//   flag stores land). Escape hatch: after ~4096 sweeps switch to agent(sc1)
//   loads permanently (covers any pathological remote writer; never triggers
//   when the ring is truly XCD-local).
// SAFE: agent loads (L3 coherence point), as in round 3.
template <int SLP>
__device__ __forceinline__ void pollA_(const int* base, int target, bool fast) {
  const int* p = base + (size_t)(threadIdx.x & 31) * 32;
  if (fast) {
    int spins = 0;
    while (1) {
      int v;
      if (spins <= 4096) {
        asm volatile("global_load_dword %0, %1, off sc0\n\t"
                     "s_waitcnt vmcnt(0)"
                     : "=v"(v) : "v"(p) : "memory");
      } else {
        v = __hip_atomic_load(p, __ATOMIC_RELAXED, __HIP_MEMORY_SCOPE_AGENT);
      }
      if (__all(v >= target)) break;
      __builtin_amdgcn_s_sleep(SLP);
      ++spins;
    }
  } else {
    while (1) {
      int v = __hip_atomic_load(p, __ATOMIC_RELAXED, __HIP_MEMORY_SCOPE_AGENT);
      if (__all(v >= target)) break;
      __builtin_amdgcn_s_sleep(SLP);
    }
  }
  asm volatile("" ::: "memory");
}

// Cross-layer poll: always agent/L3 (producer is on another XCD).
template <int SLP>
__device__ __forceinline__ void pollX_(const int* base, int target) {
  const int* p = base + (size_t)(threadIdx.x & 31) * 32;
  while (1) {
    int v = __hip_atomic_load(p, __ATOMIC_RELAXED, __HIP_MEMORY_SCOPE_AGENT);
    if (__all(v >= target)) break;
    __builtin_amdgcn_s_sleep(SLP);
  }
  asm volatile("" ::: "memory");
}

// Fused 2-layer persistent GRU scan with XCD-LOCAL rings (round 4).
// Geometry (= round 3): 256 blocks x 128 threads, role (layer,bg,g):
//   owns hidden cols [16g,16g+16) for batch rows [32bg,32bg+32); 98KB LDS
//   forces 1 block/CU -> all 256 co-resident on 256 CUs (32 CUs x 8 XCDs).
// NEW: roles are assigned at RUNTIME from physical placement. Each block
// reads HW_REG_XCC_ID, claims slot s in its XCD x -> role = x*32+s, so ring
// x (= layer x>>2, bg x&3) lives entirely on XCD x. Startup handshake
// (release/acquire total-counter) verifies every XCD claimed exactly 32
// blocks; all blocks agree on mode:
//   FAST (uniform mapping): intra-ring h exchange rides the XCD-shared L2:
//     plain b32 data stores (write-back, acked at L2 by vmcnt(0)) ->
//     __syncthreads -> plain flag store to the block's private 128B line.
//     Consumers poll sc0 (L1-bypass, L2-hit) and read h with plain b128
//     fresh-address loads (L1/L2-cold-or-valid by construction). A 128B
//     h-line spans 4 col-slices, all of the SAME ring -> same XCD -> safe.
//     ~200cyc L2 round trips replace ~900cyc L3 ones on the recurrent chain.
//   SAFE (anything else): round-3's proven agent/L3 protocol for everything;
//     spilled blocks claim leftover roles (scan loop, terminates: capacity
//     sum = block count). Mode agreement: a spill's first claim permanently
//     leaves reg[x]>32, and reg[] is monotone -> all blocks, reading after
//     total==256, compute the same mode.
// Cross-layer (L0 ring bg -> L1 ring 4+bg, inherently cross-XCD, latency-
// tolerant since L0 runs ahead): L0 producers duplicate their h0 stores to
// the SAME addresses with agent write-through (identical bytes -> L2
// writeback races harmless) and post a separate agent flag array flX; L1
// polls flX with agent loads and reads h0 with plain fresh-address loads
// (own-L2 miss -> L3 fill, which has the agent copy).
// Dataflow acyclic (L0 self-paced, L1 gates on L0) -> no deadlock; polls
// sleep-paced; graph-replay safe (dispatch-boundary cache inv/wb + memset'd
// flags, as in rounds 0-3).
__global__ __launch_bounds__(128, 1) void gru_fused(
    const float* __restrict__ x,                              // [128][256][256] fp32
    const float* __restrict__ Wih0, const float* __restrict__ Whh0,
    const float* __restrict__ bih0, const float* __restrict__ bhh0,
    const float* __restrict__ Wih1, const float* __restrict__ Whh1,
    const float* __restrict__ bih1, const float* __restrict__ bhh1,
    __bf16* __restrict__ h0base,                              // [256][128][512]
    __bf16* __restrict__ h1base,                              // [256][128][512]
    int* __restrict__ fl)                                     // flA|flX|regz (see launch)
{
  const int tid = threadIdx.x;
  int* flx  = fl + 8192;    // flX: [4 bg][32 g] lines x 32 ints
  int* regz = fl + 12288;   // reg[x] at regz[x*32], total at regz[256]

  // ---- runtime role assignment + mode handshake
  __shared__ int s_role, s_fast;
  if (tid == 0) {
    uint32_t xcc;
    asm volatile("s_getreg_b32 %0, hwreg(HW_REG_XCC_ID, 0, 32)" : "=s"(xcc));
    xcc &= 7;
    int slot = __hip_atomic_fetch_add(&regz[xcc * 32], 1,
                                      __ATOMIC_RELAXED, __HIP_MEMORY_SCOPE_AGENT);
    __hip_atomic_fetch_add(&regz[256], 1,
                           __ATOMIC_RELEASE, __HIP_MEMORY_SCOPE_AGENT);
    while (__hip_atomic_load(&regz[256], __ATOMIC_ACQUIRE,
                             __HIP_MEMORY_SCOPE_AGENT) < 256)
      __builtin_amdgcn_s_sleep(2);
    int fast = 1;
    for (int xx = 0; xx < 8; ++xx)
      fast &= (__hip_atomic_load(&regz[xx * 32], __ATOMIC_RELAXED,
                                 __HIP_MEMORY_SCOPE_AGENT) == 32);
    int role;
    if (slot < 32) {
      role = (int)xcc * 32 + slot;
    } else {                       // spill (SAFE mode): claim a leftover role
      role = -1;
      for (int xx = (int)((xcc + 1) & 7);; xx = (xx + 1) & 7) {
        int s2 = __hip_atomic_fetch_add(&regz[xx * 32], 1,
                                        __ATOMIC_RELAXED, __HIP_MEMORY_SCOPE_AGENT);
        if (s2 < 32) { role = xx * 32 + s2; break; }
        __builtin_amdgcn_s_sleep(1);
      }
    }
    s_role = role; s_fast = fast;
  }
  __syncthreads();
  const int  role  = s_role;
  const bool fast  = (bool)s_fast;
  const int  ring  = role >> 5;
  const int  g     = role & 31;
  const int  layer = ring >> 2;
  const int  bg    = ring & 3;

  const int w = tid >> 6, l = tid & 63, c = l & 15, q = l >> 4;
  const int Kin = layer ? HID : 256;
  const int KTx = Kin >> 5;            // 8 or 16
  const int KT  = KTx + 16;            // 24 or 32
  const int rowbase = bg * 32 + w * 16;
  const int jj  = g * 16 + c;

  const float* Wih = layer ? Wih1 : Wih0;
  const float* Whh = layer ? Whh1 : Whh0;
  const float* bih = layer ? bih1 : bih0;
  const float* bhh = layer ? bhh1 : bhh0;
  __bf16* hbase = layer ? h1base : h0base;

  __shared__ __bf16 ldsW[3 * 32 * 64 * 8];   // 98304 B -> 1 block/CU

  // ---- stage W slice (fp32 -> bf16) into frag-order LDS (3 tiles: r,z,n)
  for (int cid = tid; cid < 3 * KT * 64; cid += 128) {
    int nt = cid / (KT * 64);
    int r1 = cid - nt * (KT * 64);
    int kt = r1 >> 6;
    int ll = r1 & 63;
    int cc = ll & 15, qq = ll >> 4;
    int k  = kt * 32 + qq * 8;
    int grow = nt * 512 + g * 16 + cc;
    const float* src = (k < Kin) ? (Wih + (size_t)grow * Kin + k)
                                 : (Whh + (size_t)grow * HID + (k - Kin));
    bf16x8 v;
    #pragma unroll
    for (int j = 0; j < 8; ++j) v[j] = (__bf16)src[j];
    *(bf16x8*)&ldsW[((size_t)(nt * KT + kt) * 64 + ll) * 8] = v;
  }
  __syncthreads();   // LDS read-only afterwards

  // ---- hoist the h-part W fragments (3 tiles x 16 k-tiles)
  bf16x8 WH[16][3];
  #pragma unroll
  for (int kt = 0; kt < 16; ++kt) {
    WH[kt][0] = *(const bf16x8*)&ldsW[((size_t)(0 * KT + KTx + kt) * 64 + l) * 8];
    WH[kt][1] = *(const bf16x8*)&ldsW[((size_t)(1 * KT + KTx + kt) * 64 + l) * 8];
    WH[kt][2] = *(const bf16x8*)&ldsW[((size_t)(2 * KT + KTx + kt) * 64 + l) * 8];
  }

  // ---- per-lane biases (every lane owns one hidden col jj)
  const float bias_r  = bih[jj]        + bhh[jj];
  const float bias_z  = bih[512 + jj]  + bhh[512 + jj];
  const float bias_nx = bih[1024 + jj];
  const float bias_nh = bhh[1024 + jj];

  floatx4 accA[3], accB[3];
  const floatx4 zero4 = {0.f, 0.f, 0.f, 0.f};
  float hprev[4] = {0.f, 0.f, 0.f, 0.f};

  int*       fA  = fl  + ((size_t)(ring * 32 + g)) * 32;   // own flag line
  const int* fAr = fl  + ((size_t)(ring * 32)) * 32;       // own ring base
  int*       fXp = flx + ((size_t)(bg * 32 + g)) * 32;     // cross post (L0 only)
  const int* fXr = flx + ((size_t)(bg * 32)) * 32;         // cross ring (L1 watches)

  auto hslab = [&](int t) -> __bf16* {
    return hbase + (size_t)t * (BATCH * HID);
  };

  auto phaseX = [&](int t) {
    accA[0] = zero4; accA[1] = zero4; accA[2] = zero4;
    if (layer == 0) {
      const float* xp = x + ((size_t)(rowbase + c) * T_STEPS + t) * 256 + q * 8;
      for (int kt = 0; kt < 8; ++kt) {
        bf16x8 b0 = *(const bf16x8*)&ldsW[((size_t)(0 * KT + kt) * 64 + l) * 8];
        bf16x8 b1 = *(const bf16x8*)&ldsW[((size_t)(1 * KT + kt) * 64 + l) * 8];
        bf16x8 b2 = *(const bf16x8*)&ldsW[((size_t)(2 * KT + kt) * 64 + l) * 8];
        floatx4 u = *(const floatx4*)(xp + kt * 32);
        floatx4 v = *(const floatx4*)(xp + kt * 32 + 4);
        bf16x8 a;
        a[0] = (__bf16)u[0]; a[1] = (__bf16)u[1]; a[2] = (__bf16)u[2]; a[3] = (__bf16)u[3];
        a[4] = (__bf16)v[0]; a[5] = (__bf16)v[1]; a[6] = (__bf16)v[2]; a[7] = (__bf16)v[3];
        accA[0] = __builtin_amdgcn_mfma_f32_16x16x32_bf16(a, b0, accA[0], 0, 0, 0);
        accA[1] = __builtin_amdgcn_mfma_f32_16x16x32_bf16(a, b1, accA[1], 0, 0, 0);
        accA[2] = __builtin_amdgcn_mfma_f32_16x16x32_bf16(a, b2, accA[2], 0, 0, 0);
      }
    } else {
      // x = h0 slab t (caller gated on fXr); plain fresh-address loads:
      // own-L2 miss -> L3 fill (agent-dup copy) -> correct in both modes.
      const __bf16* xp = h0base + (size_t)t * (BATCH * HID)
                       + (size_t)(rowbase + c) * HID + q * 8;
      for (int kt = 0; kt < 16; ++kt) {
        bf16x8 b0 = *(const bf16x8*)&ldsW[((size_t)(0 * KT + kt) * 64 + l) * 8];
        bf16x8 b1 = *(const bf16x8*)&ldsW[((size_t)(1 * KT + kt) * 64 + l) * 8];
        bf16x8 b2 = *(const bf16x8*)&ldsW[((size_t)(2 * KT + kt) * 64 + l) * 8];
        bf16x8 a = *(const bf16x8*)(xp + kt * 32);
        accA[0] = __builtin_amdgcn_mfma_f32_16x16x32_bf16(a, b0, accA[0], 0, 0, 0);
        accA[1] = __builtin_amdgcn_mfma_f32_16x16x32_bf16(a, b1, accA[1], 0, 0, 0);
        accA[2] = __builtin_amdgcn_mfma_f32_16x16x32_bf16(a, b2, accA[2], 0, 0, 0);
      }
    }
  };

  // ---- prologue
  if (layer == 1) pollX_<2>(fXr, 1);
  phaseX(0);

  for (int t = 0; t < T_STEPS; ++t) {
    // ---- phase H: accB = h_{t-1} @ Whh_slice^T (plain cached b128 loads;
    // FAST: XCD-L2 hits; SAFE: L3 fills — both correct, fresh addresses)
    accB[0] = zero4; accB[1] = zero4; accB[2] = zero4;
    if (t > 0) {
      const __bf16* hA = hslab(t - 1) + (size_t)(rowbase + c) * HID + q * 8;
      bf16x8 hfrag[16];
      #pragma unroll
      for (int kt = 0; kt < 16; ++kt)
        hfrag[kt] = *(const bf16x8*)(hA + kt * 32);
      #pragma unroll
      for (int kt = 0; kt < 16; ++kt) {
        accB[0] = __builtin_amdgcn_mfma_f32_16x16x32_bf16(hfrag[kt], WH[kt][0], accB[0], 0, 0, 0);
        accB[1] = __builtin_amdgcn_mfma_f32_16x16x32_bf16(hfrag[kt], WH[kt][1], accB[1], 0, 0, 0);
        accB[2] = __builtin_amdgcn_mfma_f32_16x16x32_bf16(hfrag[kt], WH[kt][2], accB[2], 0, 0, 0);
      }
    }

    // ---- epilogue: gates + h update; packed-pair stores
    __bf16* hs = hslab(t);
    uint32_t vs[4];
    #pragma unroll
    for (int rg = 0; rg < 4; ++rg) {
      float r  = sigmoidf_(accA[0][rg] + accB[0][rg] + bias_r);
      float z  = sigmoidf_(accA[1][rg] + accB[1][rg] + bias_z);
      float nn = tanhf_(accA[2][rg] + bias_nx + r * (accB[2][rg] + bias_nh));
      float hnew = (1.f - z) * nn + z * hprev[rg];
      hprev[rg] = hnew;
      unsigned short us = __builtin_bit_cast(unsigned short, (__bf16)hnew);
      int po = __shfl_xor((int)us, 1, 64);
      vs[rg] = (uint32_t)us | ((uint32_t)po << 16);
    }
    if ((c & 1) == 0) {
      if (fast) {
        #pragma unroll
        for (int rg = 0; rg < 4; ++rg) {
          int row = rowbase + q * 4 + rg;
          *(volatile uint32_t*)(hs + (size_t)row * HID + jj) = vs[rg];  // own L2
        }
        if (layer == 0) {                 // agent dup for cross-XCD consumers
          asm volatile("" ::: "memory");  // keep the plain stores live
          #pragma unroll
          for (int rg = 0; rg < 4; ++rg) {
            int row = rowbase + q * 4 + rg;
            __hip_atomic_store((uint32_t*)(hs + (size_t)row * HID + jj), vs[rg],
                               __ATOMIC_RELAXED, __HIP_MEMORY_SCOPE_AGENT);
          }
        }
      } else {
        #pragma unroll
        for (int rg = 0; rg < 4; ++rg) {
          int row = rowbase + q * 4 + rg;
          __hip_atomic_store((uint32_t*)(hs + (size_t)row * HID + jj), vs[rg],
                             __ATOMIC_RELAXED, __HIP_MEMORY_SCOPE_AGENT);
        }
      }
    }

    // drain h stores (FAST: acked at own L2; SAFE: at L3), then publish t+1
    asm volatile("s_waitcnt vmcnt(0)" ::: "memory");
    __syncthreads();
    if (tid == 0) {
      if (fast) {
        *(volatile int*)fA = t + 1;                  // own ring, own L2
        if (layer == 0)
          __hip_atomic_store(fXp, t + 1, __ATOMIC_RELAXED, __HIP_MEMORY_SCOPE_AGENT);
      } else {
        __hip_atomic_store(fA, t + 1, __ATOMIC_RELAXED, __HIP_MEMORY_SCOPE_AGENT);
        if (layer == 0)
          __hip_atomic_store(fXp, t + 1, __ATOMIC_RELAXED, __HIP_MEMORY_SCOPE_AGENT);
      }
    }

    if (t + 1 < T_STEPS) {
      if (layer == 1) pollX_<2>(fXr, t + 2);   // h0 slab t+1 complete?
      phaseX(t + 1);                           // hides flag flight / x refill
      pollA_<1>(fAr, t + 1, fast);             // peers' h_t visible?
    }
  }
}

// yhat[b][o] = h1_last[b][:] . Wout[o][:] + bout[o]
__global__ __launch_bounds__(64) void outproj(const __bf16* __restrict__ h1,
                                              const float* __restrict__ Wout,
                                              const float* __restrict__ bout,
                                              float* __restrict__ out) {
  int b = blockIdx.x, o = threadIdx.x;
  const __bf16* hr = h1 + (size_t)b * HID;
  const float*  wr = Wout + (size_t)o * HID;
  float acc = bout[o];
  for (int k = 0; k < HID; k += 8) {
    bf16x8 h8 = *(const bf16x8*)(hr + k);
    #pragma unroll
    for (int j = 0; j < 8; ++j) acc += (float)h8[j] * wr[k + j];
  }
  out[b * 64 + o] = acc;
}

extern "C" void kernel_launch(void* const* d_in, const int* in_sizes, int n_in,
                              void* d_out, int out_size, void* d_ws, size_t ws_size,
                              hipStream_t stream) {
  const float* x    = (const float*)d_in[0];
  const float* Wih0 = (const float*)d_in[1];
  const float* Whh0 = (const float*)d_in[2];
  const float* bih0 = (const float*)d_in[3];
  const float* bhh0 = (const float*)d_in[4];
  const float* Wih1 = (const float*)d_in[5];
  const float* Whh1 = (const float*)d_in[6];
  const float* bih1 = (const float*)d_in[7];
  const float* bhh1 = (const float*)d_in[8];
  const float* Wout = (const float*)d_in[9];
  const float* bout = (const float*)d_in[10];

  char* ws = (char*)d_ws;
  // ws layout (bytes):
  //   [0, 32 MiB)        h0seq: 256 slabs x 128 KB ([t][b][512] bf16)
  //   [32 MiB, 64 MiB)   h1seq: 256 slabs x 128 KB
  //   [64 MiB, +64 KiB)  flA [8 ring][32 g] lines | flX [4 bg][32 g] lines |
  //                      regz (reg[8] on 128B lines + total)
  __bf16* h0 = (__bf16*)(ws);
  __bf16* h1 = (__bf16*)(ws + (32u << 20));
  int*    fl = (int*)(ws + (64u << 20));

  // zero flags + registration counters (ws is poisoned before every launch)
  (void)hipMemsetAsync(fl, 0, 64 * 1024, stream);

  gru_fused<<<256, 128, 0, stream>>>(x,
                                     Wih0, Whh0, bih0, bhh0,
                                     Wih1, Whh1, bih1, bhh1,
                                     h0, h1, fl);

  // final h1 = slab 255 (kernel-boundary release/acquire makes plain-stored
  // h1 visible to the next dispatch)
  outproj<<<128, 64, 0, stream>>>(h1 + (size_t)255 * BATCH * HID,
                                  Wout, bout, (float*)d_out);
}

// Round 5
// 1818.943 us; speedup vs baseline: 1.3955x; 1.3955x over previous
//
#include <hip/hip_runtime.h>
#include <hip/hip_bf16.h>
#include <stdint.h>

typedef __attribute__((ext_vector_type(8))) __bf16 bf16x8;
typedef __attribute__((ext_vector_type(4))) float  floatx4;

#define T_STEPS 256
#define BATCH   128
#define HID     512

__device__ __forceinline__ float sigmoidf_(float x) { return 1.f / (1.f + __expf(-x)); }
__device__ __forceinline__ float tanhf_(float y) {
  float e = __expf(-2.f * fabsf(y));
  return copysignf((1.f - e) / (1.f + e), y);
}

// poll a per-lane flag line until all 64 watched values >= target.
template <int SLP>
__device__ __forceinline__ void pollline_(const int* base, int target) {
  while (1) {
    int v = __hip_atomic_load(base, __ATOMIC_RELAXED, __HIP_MEMORY_SCOPE_AGENT);
    if (__all(v >= target)) break;
    __builtin_amdgcn_s_sleep(SLP);
  }
  asm volatile("" ::: "memory");
}

// Fused 2-layer persistent GRU scan, software-pipelined across layers.
// Grid = 256 blocks: [layer(2)][bg(2)][g(64)].
//   layer L, bg, g: owns hidden cols [8g,8g+8) for batch rows [64bg,64bg+64).
// h exchange: FRESH time-major slab per step (slab t = h after step t).
// Per-step protocol (per layer-ring, = round 0, best measured of 5 variants):
//   producer: packed 4B relaxed AGENT atomic stores -> vmcnt(0) -> barrier ->
//             plain relaxed store of t+1 to private 128B flag line.
//   consumer: poll 64 flag lines (lane l watches line l), then plain cached
//             b128 h loads (fresh addresses => no staleness possible).
// ROUND-5 change (only): the two flag GATHERS are issued early as
// non-blocking sc0-sc1 loads so their ~1 L3-RT flight hides under work that
// is on the chain anyway; the value is balloted only where round 0 would
// have started polling, with fallback to the identical blocking poll.
//   - own-ring gather: issued before phaseX(t+1), checked after it.
//   - fx gather (layer 1, t+2): issued before the epilogue; the epilogue's
//     vmcnt(0) store-drain covers its flight; checked after the flag post.
// Correctness unchanged: h data is still first-touched only after the flag
// values are confirmed >= target (visibility: flag posted after producer's
// data drain at the coherence point). Ballots read asm-loaded regs only via
// a "+v"-pinned s_waitcnt + sched_barrier(0)  (rule #18).
__global__ __launch_bounds__(256) void gru_fused(
    const float* __restrict__ x,                              // [128][256][256] fp32
    const float* __restrict__ Wih0, const float* __restrict__ Whh0,
    const float* __restrict__ bih0, const float* __restrict__ bhh0,
    const float* __restrict__ Wih1, const float* __restrict__ Whh1,
    const float* __restrict__ bih1, const float* __restrict__ bhh1,
    __bf16* __restrict__ h0base,                              // [256][128][512]
    __bf16* __restrict__ h1base,                              // [256][128][512]
    int* __restrict__ fl)                                     // [2][2][64][32]
{
  const int tid   = threadIdx.x;
  const int layer = blockIdx.x >> 7;
  const int bg    = (blockIdx.x >> 6) & 1;
  const int g     = blockIdx.x & 63;
  const int w = tid >> 6, l = tid & 63, c = l & 15, q = l >> 4;
  const int Kin = layer ? HID : 256;
  const int KTx = Kin >> 5;            // 8 or 16
  const int KT  = KTx + 16;
  const int rowbase = bg * 64 + w * 16;
  const int jj  = g * 8 + c;

  const float* Wih = layer ? Wih1 : Wih0;
  const float* Whh = layer ? Whh1 : Whh0;
  const float* bih = layer ? bih1 : bih0;
  const float* bhh = layer ? bhh1 : bhh0;
  __bf16* hbase = layer ? h1base : h0base;

  __shared__ __bf16 ldsW[2 * 32 * 64 * 8];   // 64 KiB max (KT<=32)

  // ---- stage W slice (fp32 -> bf16) into frag-order LDS
  // tile0 cols: [r0..7 | z0..7], tile1 cols: [n0..7 | zeros]
  for (int cid = tid; cid < 2 * KT * 64; cid += 256) {
    int nt = cid / (KT * 64);
    int r1 = cid - nt * (KT * 64);
    int kt = r1 >> 6;
    int ll = r1 & 63;
    int cc = ll & 15, qq = ll >> 4;
    int k  = kt * 32 + qq * 8;
    int grow;
    if (nt == 0) grow = (cc < 8) ? (g * 8 + cc) : (512 + g * 8 + (cc - 8));
    else         grow = (cc < 8) ? (1024 + g * 8 + cc) : -1;
    bf16x8 v;
    if (grow >= 0) {
      const float* src = (k < Kin) ? (Wih + (size_t)grow * Kin + k)
                                   : (Whh + (size_t)grow * HID + (k - Kin));
      #pragma unroll
      for (int j = 0; j < 8; ++j) v[j] = (__bf16)src[j];
    } else {
      #pragma unroll
      for (int j = 0; j < 8; ++j) v[j] = (__bf16)0.f;
    }
    *(bf16x8*)&ldsW[((size_t)(nt * KT + kt) * 64 + ll) * 8] = v;
  }
  __syncthreads();

  // ---- hoist the h-part W fragments
  bf16x8 WH[16][2];
  #pragma unroll
  for (int kt = 0; kt < 16; ++kt) {
    WH[kt][0] = *(const bf16x8*)&ldsW[((size_t)(0 * KT + KTx + kt) * 64 + l) * 8];
    WH[kt][1] = *(const bf16x8*)&ldsW[((size_t)(1 * KT + KTx + kt) * 64 + l) * 8];
  }

  // ---- per-lane biases
  float bias0, bias_nx, bias_nh;
  if (c < 8) {
    bias0   = bih[jj] + bhh[jj];
    bias_nx = bih[1024 + jj];
    bias_nh = bhh[1024 + jj];
  } else {
    int j2 = g * 8 + (c - 8);
    bias0   = bih[512 + j2] + bhh[512 + j2];
    bias_nx = 0.f; bias_nh = 0.f;
  }

  floatx4 accA[2], accB[2];
  const floatx4 zero4 = {0.f, 0.f, 0.f, 0.f};
  float hprev[4] = {0.f, 0.f, 0.f, 0.f};

  int* fpost      = fl + ((size_t)((layer * 2 + bg) * 64 + g)) * 32;  // private line
  const int* fown = fl + ((size_t)((layer * 2 + bg) * 64 + l)) * 32;  // own ring
  const int* fx   = fl + ((size_t)(bg * 64 + l)) * 32;                // layer-0 ring

  auto hslab = [&](int t) -> __bf16* {
    return hbase + (size_t)t * (BATCH * HID);
  };

  auto phaseX = [&](int t) {
    accA[0] = zero4; accA[1] = zero4;
    if (layer == 0) {
      const float* xp = x + ((size_t)(rowbase + c) * T_STEPS + t) * 256 + q * 8;
      for (int kt = 0; kt < 8; ++kt) {
        bf16x8 b0 = *(const bf16x8*)&ldsW[((size_t)(0 * KT + kt) * 64 + l) * 8];
        bf16x8 b1 = *(const bf16x8*)&ldsW[((size_t)(1 * KT + kt) * 64 + l) * 8];
        floatx4 u = *(const floatx4*)(xp + kt * 32);
        floatx4 v = *(const floatx4*)(xp + kt * 32 + 4);
        bf16x8 a;
        a[0] = (__bf16)u[0]; a[1] = (__bf16)u[1]; a[2] = (__bf16)u[2]; a[3] = (__bf16)u[3];
        a[4] = (__bf16)v[0]; a[5] = (__bf16)v[1]; a[6] = (__bf16)v[2]; a[7] = (__bf16)v[3];
        accA[0] = __builtin_amdgcn_mfma_f32_16x16x32_bf16(a, b0, accA[0], 0, 0, 0);
        accA[1] = __builtin_amdgcn_mfma_f32_16x16x32_bf16(a, b1, accA[1], 0, 0, 0);
      }
    } else {
      const __bf16* xp = h0base + (size_t)t * (BATCH * HID)
                       + (size_t)(rowbase + c) * HID + q * 8;
      for (int kt = 0; kt < 16; ++kt) {
        bf16x8 b0 = *(const bf16x8*)&ldsW[((size_t)(0 * KT + kt) * 64 + l) * 8];
        bf16x8 b1 = *(const bf16x8*)&ldsW[((size_t)(1 * KT + kt) * 64 + l) * 8];
        bf16x8 a = *(const bf16x8*)(xp + kt * 32);
        accA[0] = __builtin_amdgcn_mfma_f32_16x16x32_bf16(a, b0, accA[0], 0, 0, 0);
        accA[1] = __builtin_amdgcn_mfma_f32_16x16x32_bf16(a, b1, accA[1], 0, 0, 0);
      }
    }
  };

  // ---- prologue
  if (layer == 1) pollline_<2>(fx, 1);
  phaseX(0);

  for (int t = 0; t < T_STEPS; ++t) {
    // ---- phase H: accB = h_{t-1} @ Whh_slice^T (plain cached b128 loads)
    accB[0] = zero4; accB[1] = zero4;
    if (t > 0) {
      const __bf16* hA = hslab(t - 1) + (size_t)(rowbase + c) * HID + q * 8;
      bf16x8 hfrag[16];
      #pragma unroll
      for (int kt = 0; kt < 16; ++kt)
        hfrag[kt] = *(const bf16x8*)(hA + kt * 32);
      #pragma unroll
      for (int kt = 0; kt < 16; ++kt) {
        accB[0] = __builtin_amdgcn_mfma_f32_16x16x32_bf16(hfrag[kt], WH[kt][0], accB[0], 0, 0, 0);
        accB[1] = __builtin_amdgcn_mfma_f32_16x16x32_bf16(hfrag[kt], WH[kt][1], accB[1], 0, 0, 0);
      }
    }

    // ---- early fx(t+2) gather (layer 1): non-blocking; its flight hides
    // under the epilogue + vmcnt(0) store-drain below.  [round-5]
    int vfx = 0x7fffffff;
    if (layer == 1 && t + 1 < T_STEPS)
      asm volatile("global_load_dword %0, %1, off sc0 sc1"
                   : "=v"(vfx) : "v"(fx));

    // ---- epilogue: gates + h update; packed-pair agent stores (write-through)
    __bf16* hs = hslab(t);
    #pragma unroll
    for (int rg = 0; rg < 4; ++rg) {
      float pre0 = accA[0][rg] + accB[0][rg] + bias0;
      float zs = __shfl(pre0, (l & 48) | ((c + 8) & 15), 64);
      float r  = sigmoidf_(pre0);
      float z  = sigmoidf_(zs);
      float nn = tanhf_(accA[1][rg] + bias_nx + r * (accB[1][rg] + bias_nh));
      float hnew = (1.f - z) * nn + z * hprev[rg];
      hprev[rg] = hnew;
      unsigned short us = __builtin_bit_cast(unsigned short, (__bf16)hnew);
      int po = __shfl_xor((int)us, 1, 64);
      if (c < 8 && (c & 1) == 0) {
        uint32_t v = (uint32_t)us | ((uint32_t)po << 16);
        int row = rowbase + q * 4 + rg;
        __hip_atomic_store((uint32_t*)(hs + (size_t)row * HID + jj), v,
                           __ATOMIC_RELAXED, __HIP_MEMORY_SCOPE_AGENT);
      }
    }

    // drain all waves' h stores, then publish step t completion
    asm volatile("s_waitcnt vmcnt(0)" ::: "memory");
    __syncthreads();
    if (tid == 0)
      __hip_atomic_store(fpost, t + 1, __ATOMIC_RELAXED, __HIP_MEMORY_SCOPE_AGENT);

    if (t + 1 < T_STEPS) {
      if (layer == 1) {
        // vfx landed during the store-drain; pin the ballot after a waitcnt
        // that carries vfx as data dependence (rule #18), fallback = round-0.
        asm volatile("s_waitcnt vmcnt(0)" : "+v"(vfx) :: "memory");
        __builtin_amdgcn_sched_barrier(0);
        if (!__all(vfx >= t + 2)) pollline_<2>(fx, t + 2);
      }
      // ---- early own-ring gather: issue before phaseX, check after it, so
      // the gather flight hides under phaseX's loads+MFMA.  [round-5]
      int v0;
      asm volatile("global_load_dword %0, %1, off sc0 sc1"
                   : "=v"(v0) : "v"(fown));
      phaseX(t + 1);                            // hides flag flight / x refill
      asm volatile("s_waitcnt vmcnt(0)" : "+v"(v0) :: "memory");
      __builtin_amdgcn_sched_barrier(0);
      if (!__all(v0 >= t + 1)) pollline_<1>(fown, t + 1);
      // no trailing barrier: waves are independent (LDS is read-only here)
    }
  }
}

// yhat[b][o] = h1_last[b][:] . Wout[o][:] + bout[o]
__global__ __launch_bounds__(64) void outproj(const __bf16* __restrict__ h1,
                                              const float* __restrict__ Wout,
                                              const float* __restrict__ bout,
                                              float* __restrict__ out) {
  int b = blockIdx.x, o = threadIdx.x;
  const __bf16* hr = h1 + (size_t)b * HID;
  const float*  wr = Wout + (size_t)o * HID;
  float acc = bout[o];
  for (int k = 0; k < HID; k += 8) {
    bf16x8 h8 = *(const bf16x8*)(hr + k);
    #pragma unroll
    for (int j = 0; j < 8; ++j) acc += (float)h8[j] * wr[k + j];
  }
  out[b * 64 + o] = acc;
}

extern "C" void kernel_launch(void* const* d_in, const int* in_sizes, int n_in,
                              void* d_out, int out_size, void* d_ws, size_t ws_size,
                              hipStream_t stream) {
  const float* x    = (const float*)d_in[0];
  const float* Wih0 = (const float*)d_in[1];
  const float* Whh0 = (const float*)d_in[2];
  const float* bih0 = (const float*)d_in[3];
  const float* bhh0 = (const float*)d_in[4];
  const float* Wih1 = (const float*)d_in[5];
  const float* Whh1 = (const float*)d_in[6];
  const float* bih1 = (const float*)d_in[7];
  const float* bhh1 = (const float*)d_in[8];
  const float* Wout = (const float*)d_in[9];
  const float* bout = (const float*)d_in[10];

  char* ws = (char*)d_ws;
  // ws layout (bytes):
  //   [0, 32 MiB)        h0seq: 256 slabs x 128 KB ([t][b][512] bf16)
  //   [32 MiB, 64 MiB)   h1seq: 256 slabs x 128 KB
  //   [64 MiB, +64 KiB)  flags [2 layer][2 bg][64 g][32 ints] (128B lines)
  __bf16* h0 = (__bf16*)(ws);
  __bf16* h1 = (__bf16*)(ws + (32u << 20));
  int*    fl = (int*)(ws + (64u << 20));

  // zero the flag lines (ws is poisoned before every launch)
  (void)hipMemsetAsync(fl, 0, 2 * 2 * 64 * 32 * 4, stream);

  // fused 2-layer pipelined scan: blocks [0,128) = layer 0, [128,256) = layer 1
  gru_fused<<<256, 256, 0, stream>>>(x,
                                     Wih0, Whh0, bih0, bhh0,
                                     Wih1, Whh1, bih1, bhh1,
                                     h0, h1, fl);

  // final h1 = slab 255
  outproj<<<128, 64, 0, stream>>>(h1 + (size_t)255 * BATCH * HID,
                                  Wout, bout, (float*)d_out);
}

// Round 7
// 1811.636 us; speedup vs baseline: 1.4011x; 1.0040x over previous
//
#include <hip/hip_runtime.h>
#include <hip/hip_bf16.h>
#include <stdint.h>

typedef __attribute__((ext_vector_type(8))) __bf16 bf16x8;
typedef __attribute__((ext_vector_type(4))) float  floatx4;
typedef __attribute__((ext_vector_type(4))) unsigned int uintx4;

#define T_STEPS 256
#define BATCH   128
#define HID     512
#define FLS     16   // ints per flag line (64B): 1024 lines fit in 64 KiB

__device__ __forceinline__ float sigmoidf_(float x) { return 1.f / (1.f + __expf(-x)); }
__device__ __forceinline__ float tanhf_(float y) {
  float e = __expf(-2.f * fabsf(y));
  return copysignf((1.f - e) / (1.f + e), y);
}

// poll a per-lane flag line until all 64 watched values >= target.
template <int SLP>
__device__ __forceinline__ void pollline_(const int* base, int target) {
  while (1) {
    int v = __hip_atomic_load(base, __ATOMIC_RELAXED, __HIP_MEMORY_SCOPE_AGENT);
    if (__all(v >= target)) break;
    __builtin_amdgcn_s_sleep(SLP);
  }
  asm volatile("" ::: "memory");
}

// Fused 2-layer persistent GRU scan, software-pipelined across layers.
// Grid = 256 blocks: [layer(2)][bg(2)][g(64)], 256 thr (4 waves).
//   layer L, bg, g: owns hidden cols [8g,8g+8) for batch rows [64bg,64bg+64);
//   wave w handles rows [64bg+16w, +16).
// h exchange: FRESH time-major slab per step (slab t = h after step t).
// ROUND-7 = round-6 design with the flag array compressed to 64B lines so
// total workspace touch stays at 64 MiB + 64 KiB (proven-writable envelope;
// round-6's 128 KiB flag area is the prime suspect for the container fault).
//  1. PER-WAVE flags, NO in-loop __syncthreads. The exchange is exactly
//     wave-w-to-wave-w (consumer wave w reads only rows [16w,+16) of each
//     producer block = producer wave w's output). Each wave drains its own
//     stores and posts its own 64B line [layer][bg][w][g]; consumers poll
//     the 64 lines of their own w. Removes the per-step max-over-4-waves
//     straggler amplification from the chain.
//  2. 16B packed h stores: 3 shfl_xor rounds gather cols 0..7 into lane c==0
//     -> one global_store_dwordx4 sc0 sc1 per (q,rg) instead of 4B pairs.
//     4x fewer L3 write transactions (full-sector writes), faster drain ack.
//  3. Layer-1 drain rides the fx poll: stores -> fx poll (its internal
//     vmcnt(0) waits for our stores too) -> post -> phaseX -> own poll.
// Protocol guarantee unchanged: a wave's flag (t+1) is stored only after
// vmcnt(0) on its write-through data stores => consumer that observes the
// flag and THEN first-touches the fresh slab addresses reads final data.
// Dataflow acyclic (L0 free-runs; L1 gates on L0 only) -> no deadlock.
__global__ __launch_bounds__(256) void gru_fused(
    const float* __restrict__ x,                              // [128][256][256] fp32
    const float* __restrict__ Wih0, const float* __restrict__ Whh0,
    const float* __restrict__ bih0, const float* __restrict__ bhh0,
    const float* __restrict__ Wih1, const float* __restrict__ Whh1,
    const float* __restrict__ bih1, const float* __restrict__ bhh1,
    __bf16* __restrict__ h0base,                              // [256][128][512]
    __bf16* __restrict__ h1base,                              // [256][128][512]
    int* __restrict__ fl)                                     // [2][2][4][64] x FLS ints
{
  const int tid   = threadIdx.x;
  const int layer = blockIdx.x >> 7;
  const int bg    = (blockIdx.x >> 6) & 1;
  const int g     = blockIdx.x & 63;
  const int w = tid >> 6, l = tid & 63, c = l & 15, q = l >> 4;
  const int Kin = layer ? HID : 256;
  const int KTx = Kin >> 5;            // 8 or 16
  const int KT  = KTx + 16;
  const int rowbase = bg * 64 + w * 16;
  const int jj  = g * 8 + c;

  const float* Wih = layer ? Wih1 : Wih0;
  const float* Whh = layer ? Whh1 : Whh0;
  const float* bih = layer ? bih1 : bih0;
  const float* bhh = layer ? bhh1 : bhh0;
  __bf16* hbase = layer ? h1base : h0base;

  __shared__ __bf16 ldsW[2 * 32 * 64 * 8];   // 64 KiB max (KT<=32)

  // ---- stage W slice (fp32 -> bf16) into frag-order LDS
  // tile0 cols: [r0..7 | z0..7], tile1 cols: [n0..7 | zeros]
  for (int cid = tid; cid < 2 * KT * 64; cid += 256) {
    int nt = cid / (KT * 64);
    int r1 = cid - nt * (KT * 64);
    int kt = r1 >> 6;
    int ll = r1 & 63;
    int cc = ll & 15, qq = ll >> 4;
    int k  = kt * 32 + qq * 8;
    int grow;
    if (nt == 0) grow = (cc < 8) ? (g * 8 + cc) : (512 + g * 8 + (cc - 8));
    else         grow = (cc < 8) ? (1024 + g * 8 + cc) : -1;
    bf16x8 v;
    if (grow >= 0) {
      const float* src = (k < Kin) ? (Wih + (size_t)grow * Kin + k)
                                   : (Whh + (size_t)grow * HID + (k - Kin));
      #pragma unroll
      for (int j = 0; j < 8; ++j) v[j] = (__bf16)src[j];
    } else {
      #pragma unroll
      for (int j = 0; j < 8; ++j) v[j] = (__bf16)0.f;
    }
    *(bf16x8*)&ldsW[((size_t)(nt * KT + kt) * 64 + ll) * 8] = v;
  }
  __syncthreads();   // only barrier in the kernel; LDS read-only afterwards

  // ---- hoist the h-part W fragments
  bf16x8 WH[16][2];
  #pragma unroll
  for (int kt = 0; kt < 16; ++kt) {
    WH[kt][0] = *(const bf16x8*)&ldsW[((size_t)(0 * KT + KTx + kt) * 64 + l) * 8];
    WH[kt][1] = *(const bf16x8*)&ldsW[((size_t)(1 * KT + KTx + kt) * 64 + l) * 8];
  }

  // ---- per-lane biases
  float bias0, bias_nx, bias_nh;
  if (c < 8) {
    bias0   = bih[jj] + bhh[jj];
    bias_nx = bih[1024 + jj];
    bias_nh = bhh[1024 + jj];
  } else {
    int j2 = g * 8 + (c - 8);
    bias0   = bih[512 + j2] + bhh[512 + j2];
    bias_nx = 0.f; bias_nh = 0.f;
  }

  floatx4 accA[2], accB[2];
  const floatx4 zero4 = {0.f, 0.f, 0.f, 0.f};
  float hprev[4] = {0.f, 0.f, 0.f, 0.f};

  // per-WAVE flag lines: [layer][bg][w][g], 64B apart
  int*       fpost = fl + ((size_t)(((layer * 2 + bg) * 4 + w) * 64 + g)) * FLS;
  const int* fown  = fl + ((size_t)(((layer * 2 + bg) * 4 + w) * 64 + l)) * FLS;
  const int* fx    = fl + ((size_t)(((0     * 2 + bg) * 4 + w) * 64 + l)) * FLS;

  auto hslab = [&](int t) -> __bf16* {
    return hbase + (size_t)t * (BATCH * HID);
  };

  auto phaseX = [&](int t) {
    accA[0] = zero4; accA[1] = zero4;
    if (layer == 0) {
      const float* xp = x + ((size_t)(rowbase + c) * T_STEPS + t) * 256 + q * 8;
      for (int kt = 0; kt < 8; ++kt) {
        bf16x8 b0 = *(const bf16x8*)&ldsW[((size_t)(0 * KT + kt) * 64 + l) * 8];
        bf16x8 b1 = *(const bf16x8*)&ldsW[((size_t)(1 * KT + kt) * 64 + l) * 8];
        floatx4 u = *(const floatx4*)(xp + kt * 32);
        floatx4 v = *(const floatx4*)(xp + kt * 32 + 4);
        bf16x8 a;
        a[0] = (__bf16)u[0]; a[1] = (__bf16)u[1]; a[2] = (__bf16)u[2]; a[3] = (__bf16)u[3];
        a[4] = (__bf16)v[0]; a[5] = (__bf16)v[1]; a[6] = (__bf16)v[2]; a[7] = (__bf16)v[3];
        accA[0] = __builtin_amdgcn_mfma_f32_16x16x32_bf16(a, b0, accA[0], 0, 0, 0);
        accA[1] = __builtin_amdgcn_mfma_f32_16x16x32_bf16(a, b1, accA[1], 0, 0, 0);
      }
    } else {
      const __bf16* xp = h0base + (size_t)t * (BATCH * HID)
                       + (size_t)(rowbase + c) * HID + q * 8;
      for (int kt = 0; kt < 16; ++kt) {
        bf16x8 b0 = *(const bf16x8*)&ldsW[((size_t)(0 * KT + kt) * 64 + l) * 8];
        bf16x8 b1 = *(const bf16x8*)&ldsW[((size_t)(1 * KT + kt) * 64 + l) * 8];
        bf16x8 a = *(const bf16x8*)(xp + kt * 32);
        accA[0] = __builtin_amdgcn_mfma_f32_16x16x32_bf16(a, b0, accA[0], 0, 0, 0);
        accA[1] = __builtin_amdgcn_mfma_f32_16x16x32_bf16(a, b1, accA[1], 0, 0, 0);
      }
    }
  };

  // ---- prologue (per-wave fx gate)
  if (layer == 1) pollline_<2>(fx, 1);
  phaseX(0);

  for (int t = 0; t < T_STEPS; ++t) {
    // ---- phase H: accB = h_{t-1} @ Whh_slice^T (plain cached b128 loads)
    accB[0] = zero4; accB[1] = zero4;
    if (t > 0) {
      const __bf16* hA = hslab(t - 1) + (size_t)(rowbase + c) * HID + q * 8;
      bf16x8 hfrag[16];
      #pragma unroll
      for (int kt = 0; kt < 16; ++kt)
        hfrag[kt] = *(const bf16x8*)(hA + kt * 32);
      #pragma unroll
      for (int kt = 0; kt < 16; ++kt) {
        accB[0] = __builtin_amdgcn_mfma_f32_16x16x32_bf16(hfrag[kt], WH[kt][0], accB[0], 0, 0, 0);
        accB[1] = __builtin_amdgcn_mfma_f32_16x16x32_bf16(hfrag[kt], WH[kt][1], accB[1], 0, 0, 0);
      }
    }

    // ---- epilogue: gates + h update; 16B packed write-through stores.
    // 3 shfl_xor rounds gather cols (g*8+0..7) of row rowbase+q*4+rg into
    // lane c==0 as 4 dwords -> one dwordx4 sc0 sc1 store per (q,rg).
    __bf16* hs = hslab(t);
    #pragma unroll
    for (int rg = 0; rg < 4; ++rg) {
      float pre0 = accA[0][rg] + accB[0][rg] + bias0;
      float zs = __shfl(pre0, (l & 48) | ((c + 8) & 15), 64);
      float r  = sigmoidf_(pre0);
      float z  = sigmoidf_(zs);
      float nn = tanhf_(accA[1][rg] + bias_nx + r * (accB[1][rg] + bias_nh));
      float hnew = (1.f - z) * nn + z * hprev[rg];
      hprev[rg] = hnew;
      unsigned int us = (unsigned int)__builtin_bit_cast(unsigned short, (__bf16)hnew);
      unsigned int v01 = us | ((unsigned int)__shfl_xor((int)us, 1, 64) << 16);
      unsigned int v23 = (unsigned int)__shfl_xor((int)v01, 2, 64);
      unsigned int v45 = (unsigned int)__shfl_xor((int)v01, 4, 64);
      unsigned int v67 = (unsigned int)__shfl_xor((int)v23, 4, 64);
      if (c == 0) {
        uintx4 pv = {v01, v23, v45, v67};
        int row = rowbase + q * 4 + rg;
        void* dst = (void*)(hs + (size_t)row * HID + g * 8);
        asm volatile("global_store_dwordx4 %0, %1, off sc0 sc1"
                     :: "v"(dst), "v"(pv) : "memory");
      }
    }

    if (layer == 1 && t + 1 < T_STEPS) {
      // fx poll's internal waitcnt also drains our h stores: detect and
      // drain share one round trip.
      pollline_<2>(fx, t + 2);
    }
    // drain THIS wave's h stores (cheap/no-op for layer 1 after the poll),
    // then post this wave's own flag -- no block barrier.
    asm volatile("s_waitcnt vmcnt(0)" ::: "memory");
    if (l == 0)
      __hip_atomic_store(fpost, t + 1, __ATOMIC_RELAXED, __HIP_MEMORY_SCOPE_AGENT);

    if (t + 1 < T_STEPS) {
      phaseX(t + 1);                            // hides flag flight / x refill
      pollline_<1>(fown, t + 1);                // peers' wave-w h_t visible?
    }
  }
}

// yhat[b][o] = h1_last[b][:] . Wout[o][:] + bout[o]
__global__ __launch_bounds__(64) void outproj(const __bf16* __restrict__ h1,
                                              const float* __restrict__ Wout,
                                              const float* __restrict__ bout,
                                              float* __restrict__ out) {
  int b = blockIdx.x, o = threadIdx.x;
  const __bf16* hr = h1 + (size_t)b * HID;
  const float*  wr = Wout + (size_t)o * HID;
  float acc = bout[o];
  for (int k = 0; k < HID; k += 8) {
    bf16x8 h8 = *(const bf16x8*)(hr + k);
    #pragma unroll
    for (int j = 0; j < 8; ++j) acc += (float)h8[j] * wr[k + j];
  }
  out[b * 64 + o] = acc;
}

extern "C" void kernel_launch(void* const* d_in, const int* in_sizes, int n_in,
                              void* d_out, int out_size, void* d_ws, size_t ws_size,
                              hipStream_t stream) {
  const float* x    = (const float*)d_in[0];
  const float* Wih0 = (const float*)d_in[1];
  const float* Whh0 = (const float*)d_in[2];
  const float* bih0 = (const float*)d_in[3];
  const float* bhh0 = (const float*)d_in[4];
  const float* Wih1 = (const float*)d_in[5];
  const float* Whh1 = (const float*)d_in[6];
  const float* bih1 = (const float*)d_in[7];
  const float* bhh1 = (const float*)d_in[8];
  const float* Wout = (const float*)d_in[9];
  const float* bout = (const float*)d_in[10];

  char* ws = (char*)d_ws;
  // ws layout (bytes):
  //   [0, 32 MiB)        h0seq: 256 slabs x 128 KB ([t][b][512] bf16)
  //   [32 MiB, 64 MiB)   h1seq: 256 slabs x 128 KB
  //   [64 MiB, +64 KiB)  flags [2 layer][2 bg][4 w][64 g] x 16 ints (64B lines)
  __bf16* h0 = (__bf16*)(ws);
  __bf16* h1 = (__bf16*)(ws + (32u << 20));
  int*    fl = (int*)(ws + (64u << 20));

  // zero the flag lines (ws is poisoned before every launch)
  (void)hipMemsetAsync(fl, 0, 2 * 2 * 4 * 64 * FLS * 4, stream);

  // fused 2-layer pipelined scan: blocks [0,128) = layer 0, [128,256) = layer 1
  gru_fused<<<256, 256, 0, stream>>>(x,
                                     Wih0, Whh0, bih0, bhh0,
                                     Wih1, Whh1, bih1, bhh1,
                                     h0, h1, fl);

  // final h1 = slab 255
  outproj<<<128, 64, 0, stream>>>(h1 + (size_t)255 * BATCH * HID,
                                  Wout, bout, (float*)d_out);
}